// Round 7
// baseline (1988.918 us; speedup 1.0000x reference)
//
#include <hip/hip_runtime.h>
#include <math.h>

#define Bb 2
#define Ss 2048
#define Dd 1024
#define Hh 16
#define HDd 64
#define KSEL 1024           // k = S * (1 - 0.5)
#define MROWS 4096          // B*S

__device__ __forceinline__ unsigned f2u(float f) {
    unsigned u = __float_as_uint(f);
    return (u & 0x80000000u) ? ~u : (u | 0x80000000u);
}

// ---------------------------------------------------------------------------
// GEMM body: C(128x128) tile of  Y = X @ W^T (+bias), X: Mx1024, W: 1024x1024
// 256 threads, 8x8 microtile. TRANSPOSED=1 writes Y as [B][H][S][HD].
// ---------------------------------------------------------------------------
template <int TRANSPOSED>
__device__ __forceinline__ void gemm_body_1024(const float* __restrict__ X,
                                               const float* __restrict__ W,
                                               const float* __restrict__ bias,
                                               float* __restrict__ Y,
                                               int m0, int n0) {
    const int tid = threadIdx.x;
    const int tx = tid & 15, ty = tid >> 4;

    __shared__ __align__(16) float As[16][128];
    __shared__ __align__(16) float Bs[16][128];

    float acc[8][8];
#pragma unroll
    for (int i = 0; i < 8; ++i)
#pragma unroll
        for (int j = 0; j < 8; ++j) acc[i][j] = 0.f;

    for (int k0 = 0; k0 < 1024; k0 += 16) {
#pragma unroll
        for (int c = 0; c < 2; ++c) {
            int idx = tid + c * 256;
            int row = idx >> 2;
            int kq  = (idx & 3) << 2;
            float4 va = *(const float4*)&X[(size_t)(m0 + row) * 1024 + k0 + kq];
            As[kq + 0][row] = va.x; As[kq + 1][row] = va.y;
            As[kq + 2][row] = va.z; As[kq + 3][row] = va.w;
            float4 vb = *(const float4*)&W[(size_t)(n0 + row) * 1024 + k0 + kq];
            Bs[kq + 0][row] = vb.x; Bs[kq + 1][row] = vb.y;
            Bs[kq + 2][row] = vb.z; Bs[kq + 3][row] = vb.w;
        }
        __syncthreads();
#pragma unroll
        for (int kk = 0; kk < 16; ++kk) {
            float a[8], b[8];
            *(float4*)&a[0] = *(const float4*)&As[kk][ty * 4];
            *(float4*)&a[4] = *(const float4*)&As[kk][64 + ty * 4];
            *(float4*)&b[0] = *(const float4*)&Bs[kk][tx * 4];
            *(float4*)&b[4] = *(const float4*)&Bs[kk][64 + tx * 4];
#pragma unroll
            for (int i = 0; i < 8; ++i)
#pragma unroll
                for (int j = 0; j < 8; ++j) acc[i][j] = fmaf(a[i], b[j], acc[i][j]);
        }
        __syncthreads();
    }

#pragma unroll
    for (int i = 0; i < 8; ++i) {
        int m = m0 + ((i < 4) ? (ty * 4 + i) : (64 + ty * 4 + i - 4));
#pragma unroll
        for (int jq = 0; jq < 2; ++jq) {
            int n = n0 + jq * 64 + tx * 4;
            float4 bv = *(const float4*)&bias[n];
            float4 v;
            v.x = acc[i][jq * 4 + 0] + bv.x;
            v.y = acc[i][jq * 4 + 1] + bv.y;
            v.z = acc[i][jq * 4 + 2] + bv.z;
            v.w = acc[i][jq * 4 + 3] + bv.w;
            if (TRANSPOSED) {
                int bi = m >> 11, s = m & 2047;
                int h = n >> 6, d = n & 63;
                *(float4*)&Y[(((size_t)(bi * Hh + h)) * Ss + s) * HDd + d] = v;
            } else {
                *(float4*)&Y[(size_t)m * 1024 + n] = v;
            }
        }
    }
}

// QKV fused: grid (N/128=8, M/128=32, 3)
__global__ __launch_bounds__(256) void qkv_kernel(
    const float* __restrict__ q, const float* __restrict__ k, const float* __restrict__ v,
    const float* __restrict__ Wq, const float* __restrict__ Wk, const float* __restrict__ Wv,
    const float* __restrict__ bq, const float* __restrict__ bk, const float* __restrict__ bv,
    float* __restrict__ Qo, float* __restrict__ Ko, float* __restrict__ Vo) {
    int z = blockIdx.z;
    const float* X = (z == 0) ? q : ((z == 1) ? k : v);
    const float* W = (z == 0) ? Wq : ((z == 1) ? Wk : Wv);
    const float* bias = (z == 0) ? bq : ((z == 1) ? bk : bv);
    float* Y = (z == 0) ? Qo : ((z == 1) ? Ko : Vo);
    gemm_body_1024<1>(X, W, bias, Y, blockIdx.y * 128, blockIdx.x * 128);
}

// out = O @ Wo^T + bo : grid (8, 32)
__global__ __launch_bounds__(256) void outproj_kernel(
    const float* __restrict__ O, const float* __restrict__ Wo,
    const float* __restrict__ bo, float* __restrict__ Y) {
    gemm_body_1024<0>(O, Wo, bo, Y, blockIdx.y * 128, blockIdx.x * 128);
}

// ---------------------------------------------------------------------------
// FUSED: scores (16-row strip of Q_bh @ K_bh^T * 0.125, kept in registers)
//      + exact per-row k-th-largest (3-pass radix select 12/10/10 bits)
//      + masked softmax + attn write. Eliminates the 537MB intermediate
//        score write + read.
// grid = 4096 blocks x 512 threads. bh = blk>>7, rows s0 = (blk&127)*16.
// Thread t owns cols 4t..4t+3 for ALL 16 rows: acc[16][4].
// LDS: 128KB buffer = K d-tile staging (phase 1) -> histograms (phase 2)
//      -> max/sum scratch (phase 3).
// ---------------------------------------------------------------------------
__global__ __launch_bounds__(512) void fused_scores_topk_kernel(
    const float* __restrict__ Q, const float* __restrict__ Kd,
    float* __restrict__ Attn) {
    const int t = threadIdx.x;
    const int bh = blockIdx.x >> 7;
    const int s0 = (blockIdx.x & 127) * 16;
    const float* Qz = Q + (size_t)bh * Ss * HDd;
    const float* Kz = Kd + (size_t)bh * Ss * HDd;
    float* Cz = Attn + (size_t)bh * Ss * Ss;

    __shared__ __align__(16) unsigned hist[32768];   // 128 KB multi-use
    __shared__ __align__(16) float QT[1024];         // QT[d][r], pre-scaled
    __shared__ unsigned gs[2048];
    __shared__ unsigned ggs[128];
    __shared__ unsigned selA[8], rkA[8], selB[8], rkB[8];
    __shared__ unsigned prefixR[16], rkR[16], uthR[16];
    __shared__ float red2[512];
    __shared__ float mxR[16], invR[16];

    float* KTf = reinterpret_cast<float*>(hist);
    float* scratch = reinterpret_cast<float*>(hist);

    // ---- stage QT[64][16] = Q rows, scaled by 0.125 (exact pow2) ----
#pragma unroll
    for (int j = 0; j < 2; ++j) {
        int idx = t + j * 512;            // 0..1023
        int r = idx >> 6, d = idx & 63;
        QT[d * 16 + r] = Qz[(size_t)(s0 + r) * 64 + d] * 0.125f;
    }
    if (t < 16) { rkR[t] = KSEL; prefixR[t] = 0u; }

    float acc[16][4];
#pragma unroll
    for (int r = 0; r < 16; ++r)
#pragma unroll
        for (int i = 0; i < 4; ++i) acc[r][i] = 0.f;

    // ---- phase 1: QK^T, d-tiles of 16, K staged d-major in LDS ----
    for (int dt = 0; dt < 4; ++dt) {
        const int d0 = dt * 16;
        __syncthreads();                  // protect KTf reuse
#pragma unroll
        for (int j = 0; j < 16; ++j) {
            int idx = t + j * 512;        // 0..8191
            int c = idx >> 2, m = idx & 3;
            float4 kv = *(const float4*)&Kz[(size_t)c * 64 + d0 + m * 4];
            KTf[(m * 4 + 0) * 2048 + c] = kv.x;
            KTf[(m * 4 + 1) * 2048 + c] = kv.y;
            KTf[(m * 4 + 2) * 2048 + c] = kv.z;
            KTf[(m * 4 + 3) * 2048 + c] = kv.w;
        }
        __syncthreads();
#pragma unroll
        for (int kk = 0; kk < 16; ++kk) {
            float a[16], b[4];
            *(float4*)&a[0]  = *(const float4*)&QT[(d0 + kk) * 16 + 0];
            *(float4*)&a[4]  = *(const float4*)&QT[(d0 + kk) * 16 + 4];
            *(float4*)&a[8]  = *(const float4*)&QT[(d0 + kk) * 16 + 8];
            *(float4*)&a[12] = *(const float4*)&QT[(d0 + kk) * 16 + 12];
            *(float4*)&b[0]  = *(const float4*)&KTf[kk * 2048 + 4 * t];
#pragma unroll
            for (int r = 0; r < 16; ++r)
#pragma unroll
                for (int i = 0; i < 4; ++i) acc[r][i] = fmaf(a[r], b[i], acc[r][i]);
        }
    }
    __syncthreads();

    uint4 zz; zz.x = 0u; zz.y = 0u; zz.z = 0u; zz.w = 0u;

    // ---- phase 2: selection, two groups of 8 rows ----
#pragma unroll
    for (int g = 0; g < 2; ++g) {
        // ===== pass 0: top 12 bits, hist[8][4096] =====
#pragma unroll
        for (int j = 0; j < 16; ++j) *(uint4*)&hist[(t + j * 512) * 4] = zz;
        __syncthreads();
#pragma unroll
        for (int r = 0; r < 8; ++r)
#pragma unroll
            for (int i = 0; i < 4; ++i) {
                unsigned u = f2u(acc[g * 8 + r][i]);
                atomicAdd(&hist[r * 4096 + (u >> 20)], 1u);
            }
        __syncthreads();
        // gs[8][256]: sums of 16 bins
#pragma unroll
        for (int j = 0; j < 4; ++j) {
            int idx = t + j * 512;        // 0..2047
            int r = idx >> 8, qq = idx & 255;
            unsigned s = 0;
            for (int i = 0; i < 16; ++i) s += hist[r * 4096 + qq * 16 + i];
            gs[r * 256 + qq] = s;
        }
        __syncthreads();
        if (t < 128) {                    // ggs[8][16]: sums of 16 gs
            int r = t >> 4, qq = t & 15;
            unsigned s = 0;
            for (int i = 0; i < 16; ++i) s += gs[r * 256 + qq * 16 + i];
            ggs[r * 16 + qq] = s;
        }
        __syncthreads();
        if (t < 128) {                    // level 1: crossing ggs group
            int r = t >> 4, j = t & 15;
            unsigned rk = rkR[g * 8 + r];
            unsigned suf = 0;
            for (int i = j; i < 16; ++i) suf += ggs[r * 16 + i];
            unsigned Sn = suf - ggs[r * 16 + j];
            if (suf >= rk && Sn < rk) { selA[r] = (unsigned)j; rkA[r] = rk - Sn; }
        }
        __syncthreads();
        if (t < 128) {                    // level 2: crossing gs within group
            int r = t >> 4, j = t & 15;
            unsigned rk = rkA[r];
            int base = (int)selA[r] * 16;
            unsigned suf = 0;
            for (int i = j; i < 16; ++i) suf += gs[r * 256 + base + i];
            unsigned Sn = suf - gs[r * 256 + base + j];
            if (suf >= rk && Sn < rk) { selB[r] = (unsigned)(base + j); rkB[r] = rk - Sn; }
        }
        __syncthreads();
        if (t < 128) {                    // level 3: crossing bin
            int r = t >> 4, j = t & 15;
            unsigned rk = rkB[r];
            int base = (int)selB[r] * 16;
            unsigned suf = 0;
            for (int i = j; i < 16; ++i) suf += hist[r * 4096 + base + i];
            unsigned Sn = suf - hist[r * 4096 + base + j];
            if (suf >= rk && Sn < rk) {
                prefixR[g * 8 + r] = (unsigned)(base + j);   // 12-bit bin
                rkR[g * 8 + r] = rk - Sn;
            }
        }
        __syncthreads();

        // ===== pass 1: bits [19:10], hist[8][1024] =====
#pragma unroll
        for (int j = 0; j < 4; ++j) *(uint4*)&hist[(t + j * 512) * 4] = zz;
        __syncthreads();
#pragma unroll
        for (int r = 0; r < 8; ++r) {
            unsigned pr = prefixR[g * 8 + r];
#pragma unroll
            for (int i = 0; i < 4; ++i) {
                unsigned u = f2u(acc[g * 8 + r][i]);
                if ((u >> 20) == pr) atomicAdd(&hist[r * 1024 + ((u >> 10) & 1023u)], 1u);
            }
        }
        __syncthreads();
        {                                  // gs2[8][64] into gs
            int r = t >> 6, qq = t & 63;
            unsigned s = 0;
            for (int i = 0; i < 16; ++i) s += hist[r * 1024 + qq * 16 + i];
            gs[r * 64 + qq] = s;
        }
        __syncthreads();
        if (t < 128) {                     // ggs2[8][16]: sums of 4 gs2
            int r = t >> 4, qq = t & 15;
            unsigned s = 0;
            for (int i = 0; i < 4; ++i) s += gs[r * 64 + qq * 4 + i];
            ggs[r * 16 + qq] = s;
        }
        __syncthreads();
        if (t < 128) {                     // level 1 over 16
            int r = t >> 4, j = t & 15;
            unsigned rk = rkR[g * 8 + r];
            unsigned suf = 0;
            for (int i = j; i < 16; ++i) suf += ggs[r * 16 + i];
            unsigned Sn = suf - ggs[r * 16 + j];
            if (suf >= rk && Sn < rk) { selA[r] = (unsigned)j; rkA[r] = rk - Sn; }
        }
        __syncthreads();
        if (t < 32) {                      // level 2 over 4
            int r = t >> 2, j = t & 3;
            unsigned rk = rkA[r];
            int base = (int)selA[r] * 4;
            unsigned suf = 0;
            for (int i = j; i < 4; ++i) suf += gs[r * 64 + base + i];
            unsigned Sn = suf - gs[r * 64 + base + j];
            if (suf >= rk && Sn < rk) { selB[r] = (unsigned)(base + j); rkB[r] = rk - Sn; }
        }
        __syncthreads();
        if (t < 128) {                     // level 3: bin
            int r = t >> 4, j = t & 15;
            unsigned rk = rkB[r];
            int base = (int)selB[r] * 16;
            unsigned suf = 0;
            for (int i = j; i < 16; ++i) suf += hist[r * 1024 + base + i];
            unsigned Sn = suf - hist[r * 1024 + base + j];
            if (suf >= rk && Sn < rk) {
                prefixR[g * 8 + r] = (prefixR[g * 8 + r] << 10) | (unsigned)(base + j);
                rkR[g * 8 + r] = rk - Sn;
            }
        }
        __syncthreads();

        // ===== pass 2: bits [9:0], hist[8][1024] =====
#pragma unroll
        for (int j = 0; j < 4; ++j) *(uint4*)&hist[(t + j * 512) * 4] = zz;
        __syncthreads();
#pragma unroll
        for (int r = 0; r < 8; ++r) {
            unsigned pr = prefixR[g * 8 + r];
#pragma unroll
            for (int i = 0; i < 4; ++i) {
                unsigned u = f2u(acc[g * 8 + r][i]);
                if ((u >> 10) == pr) atomicAdd(&hist[r * 1024 + (u & 1023u)], 1u);
            }
        }
        __syncthreads();
        {
            int r = t >> 6, qq = t & 63;
            unsigned s = 0;
            for (int i = 0; i < 16; ++i) s += hist[r * 1024 + qq * 16 + i];
            gs[r * 64 + qq] = s;
        }
        __syncthreads();
        if (t < 128) {
            int r = t >> 4, qq = t & 15;
            unsigned s = 0;
            for (int i = 0; i < 4; ++i) s += gs[r * 64 + qq * 4 + i];
            ggs[r * 16 + qq] = s;
        }
        __syncthreads();
        if (t < 128) {
            int r = t >> 4, j = t & 15;
            unsigned rk = rkR[g * 8 + r];
            unsigned suf = 0;
            for (int i = j; i < 16; ++i) suf += ggs[r * 16 + i];
            unsigned Sn = suf - ggs[r * 16 + j];
            if (suf >= rk && Sn < rk) { selA[r] = (unsigned)j; rkA[r] = rk - Sn; }
        }
        __syncthreads();
        if (t < 32) {
            int r = t >> 2, j = t & 3;
            unsigned rk = rkA[r];
            int base = (int)selA[r] * 4;
            unsigned suf = 0;
            for (int i = j; i < 4; ++i) suf += gs[r * 64 + base + i];
            unsigned Sn = suf - gs[r * 64 + base + j];
            if (suf >= rk && Sn < rk) { selB[r] = (unsigned)(base + j); rkB[r] = rk - Sn; }
        }
        __syncthreads();
        if (t < 128) {
            int r = t >> 4, j = t & 15;
            unsigned rk = rkB[r];
            int base = (int)selB[r] * 16;
            unsigned suf = 0;
            for (int i = j; i < 16; ++i) suf += hist[r * 1024 + base + i];
            unsigned Sn = suf - hist[r * 1024 + base + j];
            if (suf >= rk && Sn < rk)
                uthR[g * 8 + r] = (prefixR[g * 8 + r] << 10) | (unsigned)(base + j);
        }
        __syncthreads();
    }

    // ---- phase 3: row max (scratch reduce over reused buffer) ----
#pragma unroll
    for (int r = 0; r < 16; ++r) {
        float m = fmaxf(fmaxf(acc[r][0], acc[r][1]), fmaxf(acc[r][2], acc[r][3]));
        scratch[r * 512 + t] = m;
    }
    __syncthreads();
    {
        int r = t >> 5, seg = t & 31;
        float m = scratch[r * 512 + seg * 16];
        for (int i = 1; i < 16; ++i) m = fmaxf(m, scratch[r * 512 + seg * 16 + i]);
        red2[r * 32 + seg] = m;
    }
    __syncthreads();
    if (t < 16) {
        float m = red2[t * 32];
        for (int i = 1; i < 32; ++i) m = fmaxf(m, red2[t * 32 + i]);
        mxR[t] = m;
    }
    __syncthreads();

    // masked exp (overwrite acc), then sum reduce
#pragma unroll
    for (int r = 0; r < 16; ++r) {
        float mx = mxR[r];
        unsigned uth = uthR[r];
        float s = 0.f;
#pragma unroll
        for (int i = 0; i < 4; ++i) {
            unsigned u = f2u(acc[r][i]);
            float e = (u >= uth) ? __expf(acc[r][i] - mx) : 0.f;
            acc[r][i] = e;
            s += e;
        }
        scratch[r * 512 + t] = s;
    }
    __syncthreads();
    {
        int r = t >> 5, seg = t & 31;
        float s = 0.f;
        for (int i = 0; i < 16; ++i) s += scratch[r * 512 + seg * 16 + i];
        red2[r * 32 + seg] = s;
    }
    __syncthreads();
    if (t < 16) {
        float s = 0.f;
        for (int i = 0; i < 32; ++i) s += red2[t * 32 + i];
        invR[t] = 1.f / s;
    }
    __syncthreads();

    // ---- write attn ----
#pragma unroll
    for (int r = 0; r < 16; ++r) {
        float inv = invR[r];
        float4 o;
        o.x = acc[r][0] * inv; o.y = acc[r][1] * inv;
        o.z = acc[r][2] * inv; o.w = acc[r][3] * inv;
        *(float4*)&Cz[(size_t)(s0 + r) * Ss + 4 * t] = o;
    }
}

// ---------------------------------------------------------------------------
// O_bh = attn_bh (2048x2048) @ V_bh (2048x64), written into O[B][S][D] layout.
// grid (16, 32). Tile 128(M) x 64(N), K-tile 32, microtile 8x4.
// ---------------------------------------------------------------------------
__global__ __launch_bounds__(256) void pv_kernel(const float* __restrict__ A,
                                                 const float* __restrict__ V,
                                                 float* __restrict__ O) {
    const int tid = threadIdx.x;
    const int tx = tid & 15, ty = tid >> 4;
    const int z = blockIdx.y;
    const int m0 = blockIdx.x * 128;
    const int bi = z >> 4, h = z & 15;
    const float* Az = A + (size_t)z * Ss * Ss;
    const float* Vz = V + (size_t)z * Ss * HDd;

    __shared__ __align__(16) float As[32][128];
    __shared__ __align__(16) float Bs[32][64];

    float acc[8][4];
#pragma unroll
    for (int i = 0; i < 8; ++i)
#pragma unroll
        for (int j = 0; j < 4; ++j) acc[i][j] = 0.f;

    for (int k0 = 0; k0 < Ss; k0 += 32) {
#pragma unroll
        for (int c = 0; c < 4; ++c) {
            int idx = tid + c * 256;
            int row = idx >> 3;
            int kq  = (idx & 7) << 2;
            float4 va = *(const float4*)&Az[(size_t)(m0 + row) * Ss + k0 + kq];
            As[kq + 0][row] = va.x; As[kq + 1][row] = va.y;
            As[kq + 2][row] = va.z; As[kq + 3][row] = va.w;
        }
#pragma unroll
        for (int c = 0; c < 2; ++c) {
            int idx = tid + c * 256;
            int kr = idx >> 4;
            int dq = (idx & 15) << 2;
            *(float4*)&Bs[kr][dq] = *(const float4*)&Vz[(size_t)(k0 + kr) * 64 + dq];
        }
        __syncthreads();
#pragma unroll
        for (int kk = 0; kk < 32; ++kk) {
            float a[8], b[4];
            *(float4*)&a[0] = *(const float4*)&As[kk][ty * 8];
            *(float4*)&a[4] = *(const float4*)&As[kk][ty * 8 + 4];
            *(float4*)&b[0] = *(const float4*)&Bs[kk][tx * 4];
#pragma unroll
            for (int i = 0; i < 8; ++i)
#pragma unroll
                for (int j = 0; j < 4; ++j) acc[i][j] = fmaf(a[i], b[j], acc[i][j]);
        }
        __syncthreads();
    }

#pragma unroll
    for (int i = 0; i < 8; ++i) {
        int srow = m0 + ty * 8 + i;
        float4 v = {acc[i][0], acc[i][1], acc[i][2], acc[i][3]};
        *(float4*)&O[((size_t)(bi * Ss + srow)) * Dd + h * 64 + tx * 4] = v;
    }
}

// ---------------------------------------------------------------------------
extern "C" void kernel_launch(void* const* d_in, const int* in_sizes, int n_in,
                              void* d_out, int out_size, void* d_ws, size_t ws_size,
                              hipStream_t stream) {
    const float* q  = (const float*)d_in[0];
    const float* k  = (const float*)d_in[1];
    const float* v  = (const float*)d_in[2];
    const float* Wq = (const float*)d_in[3];
    const float* bq = (const float*)d_in[4];
    const float* Wk = (const float*)d_in[5];
    const float* bk = (const float*)d_in[6];
    const float* Wv = (const float*)d_in[7];
    const float* bv = (const float*)d_in[8];
    const float* Wo = (const float*)d_in[9];
    const float* bo = (const float*)d_in[10];

    float* out  = (float*)d_out;                       // [B][S][D]
    float* attn = out + (size_t)Bb * Ss * Dd;          // [B][H][S][S]

    float* ws = (float*)d_ws;
    const size_t SZ = (size_t)Bb * Ss * Dd;            // 4194304
    float* Qb = ws;
    float* Kb = ws + SZ;
    float* Vb = ws + 2 * SZ;
    float* Ob = ws + 3 * SZ;

    dim3 blk(256);

    qkv_kernel<<<dim3(8, 32, 3), blk, 0, stream>>>(q, k, v, Wq, Wk, Wv, bq, bk, bv, Qb, Kb, Vb);
    fused_scores_topk_kernel<<<dim3(4096), dim3(512), 0, stream>>>(Qb, Kb, attn);
    pv_kernel<<<dim3(16, 32), blk, 0, stream>>>(attn, Vb, Ob);
    outproj_kernel<<<dim3(8, 32), blk, 0, stream>>>(Ob, Wo, bo, out);
}